// Round 1
// baseline (468.199 us; speedup 1.0000x reference)
//
#include <hip/hip_runtime.h>
#include <hip/hip_bf16.h>
#include <math.h>

// Problem shapes (fixed by setup_inputs):
//   feats:  (6,256,64,120) (6,256,32,60) (6,256,16,30) (6,256,8,15)  fp32
//   reference_points (1,3,128,128) fp32, homography (6,4,4) fp32,
//   bev_range (6) fp32, orig_h=512, orig_w=960 (int scalars)
// Outputs (concatenated flat, fp32):
//   bev_feats (6, 1024, 128, 128)   -> 100663296 elems
//   masks     (1, 24, 128, 128)     -> 393216 elems  (order: v, l, h, w)

#define NPOS_PER_LV (128 * 128)
#define NPOS_LV (6 * NPOS_PER_LV)
#define NPOS_TOTAL (4 * NPOS_LV)
#define BEV_ELEMS (6 * 1024 * 128 * 128)

typedef float floatx4 __attribute__((ext_vector_type(4)));

// ---------------------------------------------------------------------------
// Kernel 1: per-(level, view, h, w) projection -> gather offsets + weights.
// Also writes the mask output. (verified correct rounds 1-2)
// ---------------------------------------------------------------------------
__global__ __launch_bounds__(256) void precompute_kernel(
    const float* __restrict__ rp, const float* __restrict__ homo,
    const float* __restrict__ br, const int* __restrict__ oh_p,
    const int* __restrict__ ow_p, int4* __restrict__ ws_idx,
    float4* __restrict__ ws_w, float* __restrict__ mask_out)
{
    int idx = blockIdx.x * 256 + threadIdx.x;
    int w = idx & 127;
    int h = (idx >> 7) & 127;
    int lv = idx >> 14;
    int l = lv / 6;
    int v = lv - 6 * l;

    const int HFS[4] = {64, 32, 16, 8};
    const int WFS[4] = {120, 60, 30, 15};
    int Hf = HFS[l], Wf = WFS[l];
    float oh = (float)oh_p[0], ow = (float)ow_p[0];
    float sh = (float)Hf / oh;
    float sw = (float)Wf / ow;

    float p[3];
#pragma unroll
    for (int k = 0; k < 3; ++k) {
        float x = rp[k * NPOS_PER_LV + h * 128 + w];
        float s = 1.0f / (1.0f + expf(-x));
        p[k] = s * (br[3 + k] - br[k]) + br[k];
    }

    const float* Hm = homo + v * 16;
    float c0 = sw * (Hm[0] * p[0] + Hm[1] * p[1] + Hm[2]  * p[2] + Hm[3]);
    float c1 = sh * (Hm[4] * p[0] + Hm[5] * p[1] + Hm[6]  * p[2] + Hm[7]);
    float c2 =      (Hm[8] * p[0] + Hm[9] * p[1] + Hm[10] * p[2] + Hm[11]);
    float z = fmaxf(c2, 0.05f);
    float X = c0 / z;
    float Y = c1 / z;

    float m = (X >= 0.0f && X < (float)Wf && Y >= 0.0f && Y < (float)Hf) ? 1.0f : 0.0f;
    mask_out[((v * 4 + l) * 128 + h) * 128 + w] = m;

    float x0 = floorf(X), y0 = floorf(Y);
    float wx = X - x0, wy = Y - y0;
    float x1 = x0 + 1.0f, y1 = y0 + 1.0f;
    float Wm1 = (float)(Wf - 1), Hm1 = (float)(Hf - 1);

    bool v00 = (x0 >= 0.0f) && (x0 <= Wm1) && (y0 >= 0.0f) && (y0 <= Hm1);
    bool v01 = (x1 >= 0.0f) && (x1 <= Wm1) && (y0 >= 0.0f) && (y0 <= Hm1);
    bool v10 = (x0 >= 0.0f) && (x0 <= Wm1) && (y1 >= 0.0f) && (y1 <= Hm1);
    bool v11 = (x1 >= 0.0f) && (x1 <= Wm1) && (y1 >= 0.0f) && (y1 <= Hm1);

    float4 wt;
    wt.x = v00 ? (1.0f - wx) * (1.0f - wy) : 0.0f;
    wt.y = v01 ? wx * (1.0f - wy) : 0.0f;
    wt.z = v10 ? (1.0f - wx) * wy : 0.0f;
    wt.w = v11 ? wx * wy : 0.0f;

    int xi0 = (int)fminf(fmaxf(x0, 0.0f), Wm1);
    int xi1 = (int)fminf(fmaxf(x1, 0.0f), Wm1);
    int yi0 = (int)fminf(fmaxf(y0, 0.0f), Hm1);
    int yi1 = (int)fminf(fmaxf(y1, 0.0f), Hm1);

    int4 off;
    off.x = yi0 * Wf + xi0;
    off.y = yi0 * Wf + xi1;
    off.z = yi1 * Wf + xi0;
    off.w = yi1 * Wf + xi1;

    ws_idx[idx] = off;
    ws_w[idx] = wt;
}

// ---------------------------------------------------------------------------
// Kernel T (fused, all levels): (6,256,S) -> (6,S,256).
// Nontemporal input loads (read exactly once).
// grid = (240+60+15+4 = 319, 8, 6)
// ---------------------------------------------------------------------------
__global__ __launch_bounds__(256) void transpose_all_kernel(
    const float* __restrict__ f0, const float* __restrict__ f1,
    const float* __restrict__ f2, const float* __restrict__ f3,
    float* __restrict__ t0, float* __restrict__ t1,
    float* __restrict__ t2, float* __restrict__ t3)
{
    __shared__ float tile[32][33];
    int bx = blockIdx.x;
    const float* fb; float* tb; int S, sb;
    if (bx < 240)      { fb = f0; tb = t0; S = 7680; sb = bx; }
    else if (bx < 300) { fb = f1; tb = t1; S = 1920; sb = bx - 240; }
    else if (bx < 315) { fb = f2; tb = t2; S = 480;  sb = bx - 300; }
    else               { fb = f3; tb = t3; S = 120;  sb = bx - 315; }
    int v = blockIdx.z;
    int c0 = blockIdx.y * 32;
    int s0 = sb * 32;
    fb += (size_t)v * 256 * S;
    tb += (size_t)v * S * 256;
    int tx = threadIdx.x & 31;
    int ty = threadIdx.x >> 5;

#pragma unroll
    for (int k = 0; k < 4; ++k) {
        int c = c0 + ty + 8 * k;
        int s = s0 + tx;
        tile[ty + 8 * k][tx] =
            (s < S) ? __builtin_nontemporal_load(&fb[(size_t)c * S + s]) : 0.0f;
    }
    __syncthreads();
#pragma unroll
    for (int k = 0; k < 4; ++k) {
        int s = s0 + ty + 8 * k;
        int c = c0 + tx;
        if (s < S) tb[(size_t)s * 256 + c] = tile[tx][ty + 8 * k];
    }
}

// ---------------------------------------------------------------------------
// Kernel 2 (fused, all levels): block = 32-wide w tile of one (l,v,h) row.
// Phase A: wave owns 8 positions; each corner's 256-ch vector read as ONE
//   coalesced 1KB global_load_dwordx4 (float4/lane), weighted-summed, written
//   to a 32KB LDS tile with XOR swizzle (<=2-way banks both phases).
// Phase B: (w4, c)-mapped threads read 4 b32 and emit one nontemporal
//   dwordx4 store (w-contiguous) to the (v, c_total, h, w) output.
// grid = (512, 24): x = h*4 + wtile (XCD-swizzled, see below), y = l*6 + v.
//
// XCD-chunked swizzle (T1): HW round-robins linear block id across the 8
// XCDs; 512 % 8 == 0 so for fixed by, XCD k gets bx ≡ k (mod 8). Unswizzled
// that means every XCD touches the ENTIRE feat image of every (l,v)
// (level-0 view = 7.86 MB > 4 MiB L2 -> 8x duplicated miss traffic into
// LLC). Remap bxs = (bx&7)*64 + (bx>>3) (bijective, 512 = 8*64): XCD k now
// owns the contiguous BEV band h in [16k, 16k+16) with all 4 w-tiles ->
// compact, smoothly-varying corner footprint that fits its private L2, and
// w-tiles sharing corner columns sit on the same XCD.
// ---------------------------------------------------------------------------
__global__ __launch_bounds__(256) void sample_all_kernel(
    const float* __restrict__ t0, const float* __restrict__ t1,
    const float* __restrict__ t2, const float* __restrict__ t3,
    const int4* __restrict__ ws_idx,    // [l][v][h][w]
    const float4* __restrict__ ws_w,
    float* __restrict__ out)
{
    __shared__ float tile[32 * 256];    // exactly 32 KB -> 5 blocks/CU
    int tid  = threadIdx.x;
    int wave = tid >> 6;
    int lane = tid & 63;
    int bx   = blockIdx.x;
    int bxs  = ((bx & 7) << 6) | (bx >> 3);   // XCD-chunked remap (bijective)
    int w0 = (bxs & 3) * 32;
    int h  = bxs >> 2;
    int lv = blockIdx.y;                // l*6 + v
    int l  = lv / 6;
    int v  = lv - 6 * l;

    const float* base;
    if (l == 0)      base = t0 + (size_t)v * 7680 * 256;
    else if (l == 1) base = t1 + (size_t)v * 1920 * 256;
    else if (l == 2) base = t2 + (size_t)v * 480 * 256;
    else             base = t3 + (size_t)v * 120 * 256;

    int pos_base = lv * NPOS_PER_LV + h * 128 + w0;

#pragma unroll 2
    for (int i = 0; i < 8; ++i) {
        int p = wave * 8 + i;                    // local position 0..31
        int pos = pos_base + p;
        int4 off = ws_idx[pos];
        float4 wt = ws_w[pos];
        float4 acc = {0.f, 0.f, 0.f, 0.f};
        if (wt.x + wt.y + wt.z + wt.w != 0.0f) {
            const float4* p00 = (const float4*)(base + (size_t)off.x * 256);
            const float4* p01 = (const float4*)(base + (size_t)off.y * 256);
            const float4* p10 = (const float4*)(base + (size_t)off.z * 256);
            const float4* p11 = (const float4*)(base + (size_t)off.w * 256);
            float4 f00 = p00[lane];
            float4 f01 = p01[lane];
            float4 f10 = p10[lane];
            float4 f11 = p11[lane];
            acc.x = f00.x * wt.x + f01.x * wt.y + f10.x * wt.z + f11.x * wt.w;
            acc.y = f00.y * wt.x + f01.y * wt.y + f10.y * wt.z + f11.y * wt.w;
            acc.z = f00.z * wt.x + f01.z * wt.y + f10.z * wt.z + f11.z * wt.w;
            acc.w = f00.w * wt.x + f01.w * wt.y + f10.w * wt.z + f11.w * wt.w;
        }
        // swizzled write: word = p*256 + ((4*lane) ^ pat(p)), pat = ((p>>2)&7)<<2
        int pat = ((p >> 2) & 7) << 2;
        *(float4*)&tile[p * 256 + ((4 * lane) ^ pat)] = acc;
    }
    __syncthreads();

    // Phase B: thread -> (w4 = 4*(tid&7), c = (tid>>3) + 32k)
    int w4 = (tid & 7) * 4;
    int cb = tid >> 3;                  // 0..31
    int pat = (tid & 7) << 2;           // = ((p>>2)&7)<<2 for p in [w4, w4+3]
    float* ob = out + (size_t)(v * 1024 + l * 256) * NPOS_PER_LV
                    + h * 128 + w0 + w4;
#pragma unroll
    for (int k = 0; k < 8; ++k) {
        int c = cb + 32 * k;
        int cs = c ^ pat;
        floatx4 val;
        val.x = tile[(w4 + 0) * 256 + cs];
        val.y = tile[(w4 + 1) * 256 + cs];
        val.z = tile[(w4 + 2) * 256 + cs];
        val.w = tile[(w4 + 3) * 256 + cs];
        __builtin_nontemporal_store(val, (floatx4*)(ob + (size_t)c * NPOS_PER_LV));
    }
}

// ---------------------------------------------------------------------------
// Fallback sampler (round-1 style) — only if ws_size can't hold featT.
// ---------------------------------------------------------------------------
__global__ __launch_bounds__(256) void sample_kernel_gather(
    const float* __restrict__ feat, const int4* __restrict__ ws_idx,
    const float4* __restrict__ ws_w, float* __restrict__ out,
    int Hf, int Wf, int level)
{
    int t = threadIdx.x;
    int w = t & 127;
    int c0 = t >> 7;
    int h = blockIdx.x & 127;
    int v = blockIdx.x >> 7;

    int pos = (v * 128 + h) * 128 + w;
    int4 off = ws_idx[pos];
    float4 wt = ws_w[pos];

    const int plane = Hf * Wf;
    const float* fv = feat + (size_t)v * 256 * plane;
    float* ob = out + (size_t)(v * 1024 + level * 256) * NPOS_PER_LV + h * 128 + w;

    if (wt.x + wt.y + wt.z + wt.w != 0.0f) {
#pragma unroll 4
        for (int i = 0; i < 128; ++i) {
            int c = 2 * i + c0;
            const float* fc = fv + (size_t)c * plane;
            float val = fc[off.x] * wt.x + fc[off.y] * wt.y +
                        fc[off.z] * wt.z + fc[off.w] * wt.w;
            ob[(size_t)c * NPOS_PER_LV] = val;
        }
    } else {
#pragma unroll 8
        for (int i = 0; i < 128; ++i) {
            int c = 2 * i + c0;
            ob[(size_t)c * NPOS_PER_LV] = 0.0f;
        }
    }
}

extern "C" void kernel_launch(void* const* d_in, const int* in_sizes, int n_in,
                              void* d_out, int out_size, void* d_ws, size_t ws_size,
                              hipStream_t stream) {
    const float* feats[4] = {(const float*)d_in[0], (const float*)d_in[1],
                             (const float*)d_in[2], (const float*)d_in[3]};
    const float* rp   = (const float*)d_in[4];
    const float* homo = (const float*)d_in[5];
    const float* br   = (const float*)d_in[6];
    const int* oh_p   = (const int*)d_in[7];
    const int* ow_p   = (const int*)d_in[8];

    float* out = (float*)d_out;

    int4*   ws_idx = (int4*)d_ws;
    float4* ws_w   = (float4*)((char*)d_ws + (size_t)NPOS_TOTAL * sizeof(int4));
    float*  featT  = (float*)((char*)d_ws + (size_t)NPOS_TOTAL * (sizeof(int4) + sizeof(float4)));
    float* mask_out = out + (size_t)BEV_ELEMS;

    const int HFS[4] = {64, 32, 16, 8};
    const int WFS[4] = {120, 60, 30, 15};
    const int SS[4]  = {7680, 1920, 480, 120};
    size_t featT_off[4];
    size_t acc = 0;
    for (int l = 0; l < 4; ++l) { featT_off[l] = acc; acc += (size_t)6 * 256 * SS[l]; }
    const size_t WS_NEEDED = (size_t)NPOS_TOTAL * (sizeof(int4) + sizeof(float4))
                           + acc * sizeof(float);             // ~75.5 MB

    precompute_kernel<<<NPOS_TOTAL / 256, 256, 0, stream>>>(
        rp, homo, br, oh_p, ow_p, ws_idx, ws_w, mask_out);

    if (ws_size >= WS_NEEDED) {
        dim3 tgrid(319, 8, 6);
        transpose_all_kernel<<<tgrid, 256, 0, stream>>>(
            feats[0], feats[1], feats[2], feats[3],
            featT + featT_off[0], featT + featT_off[1],
            featT + featT_off[2], featT + featT_off[3]);

        dim3 sgrid(512, 24);
        sample_all_kernel<<<sgrid, 256, 0, stream>>>(
            featT + featT_off[0], featT + featT_off[1],
            featT + featT_off[2], featT + featT_off[3],
            ws_idx, ws_w, out);
    } else {
        for (int l = 0; l < 4; ++l) {
            sample_kernel_gather<<<6 * 128, 256, 0, stream>>>(
                feats[l], ws_idx + (size_t)l * NPOS_LV, ws_w + (size_t)l * NPOS_LV,
                out, HFS[l], WFS[l], l);
        }
    }
}

// Round 2
// 466.830 us; speedup vs baseline: 1.0029x; 1.0029x over previous
//
#include <hip/hip_runtime.h>
#include <hip/hip_bf16.h>
#include <math.h>

// Problem shapes (fixed by setup_inputs):
//   feats:  (6,256,64,120) (6,256,32,60) (6,256,16,30) (6,256,8,15)  fp32
//   reference_points (1,3,128,128) fp32, homography (6,4,4) fp32,
//   bev_range (6) fp32, orig_h=512, orig_w=960 (int scalars)
// Outputs (concatenated flat, fp32):
//   bev_feats (6, 1024, 128, 128)   -> 100663296 elems
//   masks     (1, 24, 128, 128)     -> 393216 elems  (order: v, l, h, w)

#define NPOS_PER_LV (128 * 128)
#define NPOS_LV (6 * NPOS_PER_LV)
#define NPOS_TOTAL (4 * NPOS_LV)
#define BEV_ELEMS (6 * 1024 * 128 * 128)

typedef float floatx4 __attribute__((ext_vector_type(4)));

// ---------------------------------------------------------------------------
// Kernel 1: per-(level, view, h, w) projection -> gather offsets + weights.
// Also writes the mask output. (verified correct)
// ---------------------------------------------------------------------------
__global__ __launch_bounds__(256) void precompute_kernel(
    const float* __restrict__ rp, const float* __restrict__ homo,
    const float* __restrict__ br, const int* __restrict__ oh_p,
    const int* __restrict__ ow_p, int4* __restrict__ ws_idx,
    float4* __restrict__ ws_w, float* __restrict__ mask_out)
{
    int idx = blockIdx.x * 256 + threadIdx.x;
    int w = idx & 127;
    int h = (idx >> 7) & 127;
    int lv = idx >> 14;
    int l = lv / 6;
    int v = lv - 6 * l;

    const int HFS[4] = {64, 32, 16, 8};
    const int WFS[4] = {120, 60, 30, 15};
    int Hf = HFS[l], Wf = WFS[l];
    float oh = (float)oh_p[0], ow = (float)ow_p[0];
    float sh = (float)Hf / oh;
    float sw = (float)Wf / ow;

    float p[3];
#pragma unroll
    for (int k = 0; k < 3; ++k) {
        float x = rp[k * NPOS_PER_LV + h * 128 + w];
        float s = 1.0f / (1.0f + expf(-x));
        p[k] = s * (br[3 + k] - br[k]) + br[k];
    }

    const float* Hm = homo + v * 16;
    float c0 = sw * (Hm[0] * p[0] + Hm[1] * p[1] + Hm[2]  * p[2] + Hm[3]);
    float c1 = sh * (Hm[4] * p[0] + Hm[5] * p[1] + Hm[6]  * p[2] + Hm[7]);
    float c2 =      (Hm[8] * p[0] + Hm[9] * p[1] + Hm[10] * p[2] + Hm[11]);
    float z = fmaxf(c2, 0.05f);
    float X = c0 / z;
    float Y = c1 / z;

    float m = (X >= 0.0f && X < (float)Wf && Y >= 0.0f && Y < (float)Hf) ? 1.0f : 0.0f;
    mask_out[((v * 4 + l) * 128 + h) * 128 + w] = m;

    float x0 = floorf(X), y0 = floorf(Y);
    float wx = X - x0, wy = Y - y0;
    float x1 = x0 + 1.0f, y1 = y0 + 1.0f;
    float Wm1 = (float)(Wf - 1), Hm1 = (float)(Hf - 1);

    bool v00 = (x0 >= 0.0f) && (x0 <= Wm1) && (y0 >= 0.0f) && (y0 <= Hm1);
    bool v01 = (x1 >= 0.0f) && (x1 <= Wm1) && (y0 >= 0.0f) && (y0 <= Hm1);
    bool v10 = (x0 >= 0.0f) && (x0 <= Wm1) && (y1 >= 0.0f) && (y1 <= Hm1);
    bool v11 = (x1 >= 0.0f) && (x1 <= Wm1) && (y1 >= 0.0f) && (y1 <= Hm1);

    float4 wt;
    wt.x = v00 ? (1.0f - wx) * (1.0f - wy) : 0.0f;
    wt.y = v01 ? wx * (1.0f - wy) : 0.0f;
    wt.z = v10 ? (1.0f - wx) * wy : 0.0f;
    wt.w = v11 ? wx * wy : 0.0f;

    int xi0 = (int)fminf(fmaxf(x0, 0.0f), Wm1);
    int xi1 = (int)fminf(fmaxf(x1, 0.0f), Wm1);
    int yi0 = (int)fminf(fmaxf(y0, 0.0f), Hm1);
    int yi1 = (int)fminf(fmaxf(y1, 0.0f), Hm1);

    int4 off;
    off.x = yi0 * Wf + xi0;
    off.y = yi0 * Wf + xi1;
    off.z = yi1 * Wf + xi0;
    off.w = yi1 * Wf + xi1;

    ws_idx[idx] = off;
    ws_w[idx] = wt;
}

// ---------------------------------------------------------------------------
// Kernel T-A (fused, all levels, Tier A): (6,256,S) -> (6,S,256).
// grid = (240+60+15+4 = 319, 8, 6)
// ---------------------------------------------------------------------------
__global__ __launch_bounds__(256) void transpose_all_kernel(
    const float* __restrict__ f0, const float* __restrict__ f1,
    const float* __restrict__ f2, const float* __restrict__ f3,
    float* __restrict__ t0, float* __restrict__ t1,
    float* __restrict__ t2, float* __restrict__ t3)
{
    __shared__ float tile[32][33];
    int bx = blockIdx.x;
    const float* fb; float* tb; int S, sb;
    if (bx < 240)      { fb = f0; tb = t0; S = 7680; sb = bx; }
    else if (bx < 300) { fb = f1; tb = t1; S = 1920; sb = bx - 240; }
    else if (bx < 315) { fb = f2; tb = t2; S = 480;  sb = bx - 300; }
    else               { fb = f3; tb = t3; S = 120;  sb = bx - 315; }
    int v = blockIdx.z;
    int c0 = blockIdx.y * 32;
    int s0 = sb * 32;
    fb += (size_t)v * 256 * S;
    tb += (size_t)v * S * 256;
    int tx = threadIdx.x & 31;
    int ty = threadIdx.x >> 5;

#pragma unroll
    for (int k = 0; k < 4; ++k) {
        int c = c0 + ty + 8 * k;
        int s = s0 + tx;
        tile[ty + 8 * k][tx] =
            (s < S) ? __builtin_nontemporal_load(&fb[(size_t)c * S + s]) : 0.0f;
    }
    __syncthreads();
#pragma unroll
    for (int k = 0; k < 4; ++k) {
        int s = s0 + ty + 8 * k;
        int c = c0 + tx;
        if (s < S) tb[(size_t)s * 256 + c] = tile[tx][ty + 8 * k];
    }
}

// ---------------------------------------------------------------------------
// Kernel T-BC (per-level/per-view): f layout [nv][256][S] -> t [nv][S][256].
// grid = (ceil(S/32), 8, nv). v0 is pre-baked into f by the launcher.
// ---------------------------------------------------------------------------
__global__ __launch_bounds__(256) void transpose_lv_kernel(
    const float* __restrict__ f, float* __restrict__ t, int S)
{
    __shared__ float tile[32][33];
    int v = blockIdx.z;
    int c0 = blockIdx.y * 32;
    int s0 = blockIdx.x * 32;
    const float* fb = f + (size_t)v * 256 * S;
    float* tb = t + (size_t)v * S * 256;
    int tx = threadIdx.x & 31;
    int ty = threadIdx.x >> 5;

#pragma unroll
    for (int k = 0; k < 4; ++k) {
        int c = c0 + ty + 8 * k;
        int s = s0 + tx;
        tile[ty + 8 * k][tx] =
            (s < S) ? __builtin_nontemporal_load(&fb[(size_t)c * S + s]) : 0.0f;
    }
    __syncthreads();
#pragma unroll
    for (int k = 0; k < 4; ++k) {
        int s = s0 + ty + 8 * k;
        int c = c0 + tx;
        if (s < S) tb[(size_t)s * 256 + c] = tile[tx][ty + 8 * k];
    }
}

// ---------------------------------------------------------------------------
// Kernel 2-A (fused, all levels, Tier A). grid = (512, 24).
// Phase A: wave owns 8 positions; each corner's 256-ch vector read as ONE
//   coalesced 1KB global_load_dwordx4, weighted-summed, written to a 32KB
//   LDS tile with XOR swizzle. Phase B: w-contiguous nontemporal dwordx4
//   stores to (v, c_total, h, w).
// ---------------------------------------------------------------------------
__global__ __launch_bounds__(256) void sample_all_kernel(
    const float* __restrict__ t0, const float* __restrict__ t1,
    const float* __restrict__ t2, const float* __restrict__ t3,
    const int4* __restrict__ ws_idx,    // [l][v][h][w]
    const float4* __restrict__ ws_w,
    float* __restrict__ out)
{
    __shared__ float tile[32 * 256];    // exactly 32 KB -> 5 blocks/CU
    int tid  = threadIdx.x;
    int wave = tid >> 6;
    int lane = tid & 63;
    int bx   = blockIdx.x;
    int bxs  = ((bx & 7) << 6) | (bx >> 3);   // XCD-chunked remap (bijective)
    int w0 = (bxs & 3) * 32;
    int h  = bxs >> 2;
    int lv = blockIdx.y;                // l*6 + v
    int l  = lv / 6;
    int v  = lv - 6 * l;

    const float* base;
    if (l == 0)      base = t0 + (size_t)v * 7680 * 256;
    else if (l == 1) base = t1 + (size_t)v * 1920 * 256;
    else if (l == 2) base = t2 + (size_t)v * 480 * 256;
    else             base = t3 + (size_t)v * 120 * 256;

    int pos_base = lv * NPOS_PER_LV + h * 128 + w0;

#pragma unroll 2
    for (int i = 0; i < 8; ++i) {
        int p = wave * 8 + i;                    // local position 0..31
        int pos = pos_base + p;
        int4 off = ws_idx[pos];
        float4 wt = ws_w[pos];
        float4 acc = {0.f, 0.f, 0.f, 0.f};
        if (wt.x + wt.y + wt.z + wt.w != 0.0f) {
            const float4* p00 = (const float4*)(base + (size_t)off.x * 256);
            const float4* p01 = (const float4*)(base + (size_t)off.y * 256);
            const float4* p10 = (const float4*)(base + (size_t)off.z * 256);
            const float4* p11 = (const float4*)(base + (size_t)off.w * 256);
            float4 f00 = p00[lane];
            float4 f01 = p01[lane];
            float4 f10 = p10[lane];
            float4 f11 = p11[lane];
            acc.x = f00.x * wt.x + f01.x * wt.y + f10.x * wt.z + f11.x * wt.w;
            acc.y = f00.y * wt.x + f01.y * wt.y + f10.y * wt.z + f11.y * wt.w;
            acc.z = f00.z * wt.x + f01.z * wt.y + f10.z * wt.z + f11.z * wt.w;
            acc.w = f00.w * wt.x + f01.w * wt.y + f10.w * wt.z + f11.w * wt.w;
        }
        int pat = ((p >> 2) & 7) << 2;
        *(float4*)&tile[p * 256 + ((4 * lane) ^ pat)] = acc;
    }
    __syncthreads();

    int w4 = (tid & 7) * 4;
    int cb = tid >> 3;                  // 0..31
    int pat = (tid & 7) << 2;
    float* ob = out + (size_t)(v * 1024 + l * 256) * NPOS_PER_LV
                    + h * 128 + w0 + w4;
#pragma unroll
    for (int k = 0; k < 8; ++k) {
        int c = cb + 32 * k;
        int cs = c ^ pat;
        floatx4 val;
        val.x = tile[(w4 + 0) * 256 + cs];
        val.y = tile[(w4 + 1) * 256 + cs];
        val.z = tile[(w4 + 2) * 256 + cs];
        val.w = tile[(w4 + 3) * 256 + cs];
        __builtin_nontemporal_store(val, (floatx4*)(ob + (size_t)c * NPOS_PER_LV));
    }
}

// ---------------------------------------------------------------------------
// Kernel 2-BC (per-level/per-view sampler). grid = (512, nv).
// t holds featT for views v0..v0+nv-1 of level l, layout [vv][S][256].
// Body is a verbatim parametrization of sample_all_kernel.
// ---------------------------------------------------------------------------
__global__ __launch_bounds__(256) void sample_lv_kernel(
    const float* __restrict__ t,
    const int4* __restrict__ ws_idx, const float4* __restrict__ ws_w,
    float* __restrict__ out, int l, int v0, int S)
{
    __shared__ float tile[32 * 256];
    int tid  = threadIdx.x;
    int wave = tid >> 6;
    int lane = tid & 63;
    int bx   = blockIdx.x;
    int bxs  = ((bx & 7) << 6) | (bx >> 3);   // XCD-chunked remap (bijective)
    int w0 = (bxs & 3) * 32;
    int h  = bxs >> 2;
    int vv = blockIdx.y;                // 0..nv-1
    int v  = v0 + vv;

    const float* base = t + (size_t)vv * S * 256;
    int pos_base = (l * 6 + v) * NPOS_PER_LV + h * 128 + w0;

#pragma unroll 2
    for (int i = 0; i < 8; ++i) {
        int p = wave * 8 + i;
        int pos = pos_base + p;
        int4 off = ws_idx[pos];
        float4 wt = ws_w[pos];
        float4 acc = {0.f, 0.f, 0.f, 0.f};
        if (wt.x + wt.y + wt.z + wt.w != 0.0f) {
            const float4* p00 = (const float4*)(base + (size_t)off.x * 256);
            const float4* p01 = (const float4*)(base + (size_t)off.y * 256);
            const float4* p10 = (const float4*)(base + (size_t)off.z * 256);
            const float4* p11 = (const float4*)(base + (size_t)off.w * 256);
            float4 f00 = p00[lane];
            float4 f01 = p01[lane];
            float4 f10 = p10[lane];
            float4 f11 = p11[lane];
            acc.x = f00.x * wt.x + f01.x * wt.y + f10.x * wt.z + f11.x * wt.w;
            acc.y = f00.y * wt.x + f01.y * wt.y + f10.y * wt.z + f11.y * wt.w;
            acc.z = f00.z * wt.x + f01.z * wt.y + f10.z * wt.z + f11.z * wt.w;
            acc.w = f00.w * wt.x + f01.w * wt.y + f10.w * wt.z + f11.w * wt.w;
        }
        int pat = ((p >> 2) & 7) << 2;
        *(float4*)&tile[p * 256 + ((4 * lane) ^ pat)] = acc;
    }
    __syncthreads();

    int w4 = (tid & 7) * 4;
    int cb = tid >> 3;
    int pat = (tid & 7) << 2;
    float* ob = out + (size_t)(v * 1024 + l * 256) * NPOS_PER_LV
                    + h * 128 + w0 + w4;
#pragma unroll
    for (int k = 0; k < 8; ++k) {
        int c = cb + 32 * k;
        int cs = c ^ pat;
        floatx4 val;
        val.x = tile[(w4 + 0) * 256 + cs];
        val.y = tile[(w4 + 1) * 256 + cs];
        val.z = tile[(w4 + 2) * 256 + cs];
        val.w = tile[(w4 + 3) * 256 + cs];
        __builtin_nontemporal_store(val, (floatx4*)(ob + (size_t)c * NPOS_PER_LV));
    }
}

// ---------------------------------------------------------------------------
// Fallback sampler (round-1 style) — only if ws can't hold any featT tier.
// ---------------------------------------------------------------------------
__global__ __launch_bounds__(256) void sample_kernel_gather(
    const float* __restrict__ feat, const int4* __restrict__ ws_idx,
    const float4* __restrict__ ws_w, float* __restrict__ out,
    int Hf, int Wf, int level)
{
    int t = threadIdx.x;
    int w = t & 127;
    int c0 = t >> 7;
    int h = blockIdx.x & 127;
    int v = blockIdx.x >> 7;

    int pos = (v * 128 + h) * 128 + w;
    int4 off = ws_idx[pos];
    float4 wt = ws_w[pos];

    const int plane = Hf * Wf;
    const float* fv = feat + (size_t)v * 256 * plane;
    float* ob = out + (size_t)(v * 1024 + level * 256) * NPOS_PER_LV + h * 128 + w;

    if (wt.x + wt.y + wt.z + wt.w != 0.0f) {
#pragma unroll 4
        for (int i = 0; i < 128; ++i) {
            int c = 2 * i + c0;
            const float* fc = fv + (size_t)c * plane;
            float val = fc[off.x] * wt.x + fc[off.y] * wt.y +
                        fc[off.z] * wt.z + fc[off.w] * wt.w;
            ob[(size_t)c * NPOS_PER_LV] = val;
        }
    } else {
#pragma unroll 8
        for (int i = 0; i < 128; ++i) {
            int c = 2 * i + c0;
            ob[(size_t)c * NPOS_PER_LV] = 0.0f;
        }
    }
}

extern "C" void kernel_launch(void* const* d_in, const int* in_sizes, int n_in,
                              void* d_out, int out_size, void* d_ws, size_t ws_size,
                              hipStream_t stream) {
    const float* feats[4] = {(const float*)d_in[0], (const float*)d_in[1],
                             (const float*)d_in[2], (const float*)d_in[3]};
    const float* rp   = (const float*)d_in[4];
    const float* homo = (const float*)d_in[5];
    const float* br   = (const float*)d_in[6];
    const int* oh_p   = (const int*)d_in[7];
    const int* ow_p   = (const int*)d_in[8];

    float* out = (float*)d_out;

    int4*   ws_idx = (int4*)d_ws;
    float4* ws_w   = (float4*)((char*)d_ws + (size_t)NPOS_TOTAL * sizeof(int4));
    const size_t IDXW_BYTES = (size_t)NPOS_TOTAL * (sizeof(int4) + sizeof(float4)); // 12.58 MB
    float*  featT  = (float*)((char*)d_ws + IDXW_BYTES);
    float* mask_out = out + (size_t)BEV_ELEMS;

    const int HFS[4] = {64, 32, 16, 8};
    const int WFS[4] = {120, 60, 30, 15};
    const int SS[4]  = {7680, 1920, 480, 120};
    size_t featT_off[4];
    size_t acc = 0;
    for (int l = 0; l < 4; ++l) { featT_off[l] = acc; acc += (size_t)6 * 256 * SS[l]; }

    const size_t WS_A = IDXW_BYTES + acc * sizeof(float);                   // ~75.3 MB
    const size_t WS_B = IDXW_BYTES + (size_t)6 * 256 * SS[0] * sizeof(float); // ~59.8 MB
    const size_t WS_C = IDXW_BYTES + (size_t)256 * SS[0] * sizeof(float);     // ~20.5 MB

    precompute_kernel<<<NPOS_TOTAL / 256, 256, 0, stream>>>(
        rp, homo, br, oh_p, ow_p, ws_idx, ws_w, mask_out);

    if (ws_size >= WS_A) {
        // Tier A: all levels resident simultaneously (fused kernels).
        dim3 tgrid(319, 8, 6);
        transpose_all_kernel<<<tgrid, 256, 0, stream>>>(
            feats[0], feats[1], feats[2], feats[3],
            featT + featT_off[0], featT + featT_off[1],
            featT + featT_off[2], featT + featT_off[3]);

        dim3 sgrid(512, 24);
        sample_all_kernel<<<sgrid, 24 == 24 ? 256 : 256, 0, stream>>>(
            featT + featT_off[0], featT + featT_off[1],
            featT + featT_off[2], featT + featT_off[3],
            ws_idx, ws_w, out);
    } else if (ws_size >= WS_B) {
        // Tier B: per-level pipeline reusing one featT region.
        for (int l = 0; l < 4; ++l) {
            int S = SS[l];
            dim3 tgrid((S + 31) / 32, 8, 6);
            transpose_lv_kernel<<<tgrid, 256, 0, stream>>>(feats[l], featT, S);
            dim3 sgrid(512, 6);
            sample_lv_kernel<<<sgrid, 256, 0, stream>>>(
                featT, ws_idx, ws_w, out, l, /*v0=*/0, S);
        }
    } else if (ws_size >= WS_C) {
        // Tier C: per-(level,view) pipeline, featT region = one view of level 0.
        for (int l = 0; l < 4; ++l) {
            int S = SS[l];
            for (int v = 0; v < 6; ++v) {
                dim3 tgrid((S + 31) / 32, 8, 1);
                transpose_lv_kernel<<<tgrid, 256, 0, stream>>>(
                    feats[l] + (size_t)v * 256 * S, featT, S);
                dim3 sgrid(512, 1);
                sample_lv_kernel<<<sgrid, 256, 0, stream>>>(
                    featT, ws_idx, ws_w, out, l, /*v0=*/v, S);
            }
        }
    } else {
        // Fallback: channel-strided gather from original layout.
        for (int l = 0; l < 4; ++l) {
            sample_kernel_gather<<<6 * 128, 256, 0, stream>>>(
                feats[l], ws_idx + (size_t)l * NPOS_LV, ws_w + (size_t)l * NPOS_LV,
                out, HFS[l], WFS[l], l);
        }
    }
}